// Round 1
// baseline (2362.220 us; speedup 1.0000x reference)
//
#include <hip/hip_runtime.h>
#include <math.h>

#define T_TOK 16384
#define CC 256
#define PP 16
#define HH 8
#define DD 32
#define FIN 512
#define FHID 2048
#define LN_EPS 1e-5f

// ---------------------------------------------------------------------------
// Generic tiled GEMM: C[M,256] = A[M,256] @ B[256,256], 64 rows per block.
// LN_MODE==1: LayerNorm epilogue (over the 256 cols) with gamma/beta.
// ---------------------------------------------------------------------------
template<int LN_MODE>
__global__ __launch_bounds__(256) void gemm256_kernel(const float* __restrict__ A,
                                                      const float* __restrict__ Bw,
                                                      const float* __restrict__ gam,
                                                      const float* __restrict__ bet,
                                                      float* __restrict__ Cout) {
  __shared__ float As[32][68];    // [k][row], transposed A chunk
  __shared__ float Bs[32][260];   // [k][col]
  __shared__ float muL[64], rsL[64];
  const int tid = threadIdx.x;
  const int m0 = blockIdx.x * 64;
  const int tr = tid >> 5, tc = tid & 31;   // rows tr*8.., cols tc*8..
  float acc[8][8];
#pragma unroll
  for (int i = 0; i < 8; i++)
#pragma unroll
    for (int j = 0; j < 8; j++) acc[i][j] = 0.f;

  for (int k0 = 0; k0 < 256; k0 += 32) {
#pragma unroll
    for (int i = 0; i < 2; i++) {           // stage A [64 rows][32 k] transposed
      int lin = tid + i * 256, row = lin >> 3, kq = lin & 7;
      float4 av = *(const float4*)&A[(size_t)(m0 + row) * CC + k0 + kq * 4];
      As[kq * 4 + 0][row] = av.x; As[kq * 4 + 1][row] = av.y;
      As[kq * 4 + 2][row] = av.z; As[kq * 4 + 3][row] = av.w;
    }
#pragma unroll
    for (int i = 0; i < 8; i++) {           // stage B [32 k][256 n]
      int lin = tid + i * 256, bk = lin >> 6, bc = (lin & 63) * 4;
      *(float4*)&Bs[bk][bc] = *(const float4*)&Bw[(size_t)(k0 + bk) * CC + bc];
    }
    __syncthreads();
#pragma unroll
    for (int kk = 0; kk < 32; kk++) {
      float a[8], b[8];
      *(float4*)&a[0] = *(const float4*)&As[kk][tr * 8];
      *(float4*)&a[4] = *(const float4*)&As[kk][tr * 8 + 4];
      *(float4*)&b[0] = *(const float4*)&Bs[kk][tc * 8];
      *(float4*)&b[4] = *(const float4*)&Bs[kk][tc * 8 + 4];
#pragma unroll
      for (int i = 0; i < 8; i++)
#pragma unroll
        for (int j = 0; j < 8; j++) acc[i][j] += a[i] * b[j];
    }
    __syncthreads();
  }

  if constexpr (LN_MODE == 0) {
#pragma unroll
    for (int i = 0; i < 8; i++) {
      size_t row = (size_t)(m0 + tr * 8 + i);
#pragma unroll
      for (int j = 0; j < 8; j += 4) {
        float4 v = make_float4(acc[i][j], acc[i][j + 1], acc[i][j + 2], acc[i][j + 3]);
        *(float4*)&Cout[row * CC + tc * 8 + j] = v;
      }
    }
  } else {
    // LayerNorm over the 256 cols of each row; red[] aliases Bs (done with it).
    float (*red)[66] = (float (*)[66])&Bs[0][0];
#pragma unroll
    for (int i = 0; i < 8; i++) {
      float s1 = 0.f, s2 = 0.f;
#pragma unroll
      for (int j = 0; j < 8; j++) { s1 += acc[i][j]; s2 += acc[i][j] * acc[i][j]; }
      red[tr * 8 + i][tc * 2] = s1;
      red[tr * 8 + i][tc * 2 + 1] = s2;
    }
    __syncthreads();
    if (tid < 64) {
      float s1 = 0.f, s2 = 0.f;
      for (int c = 0; c < 32; c++) { s1 += red[tid][2 * c]; s2 += red[tid][2 * c + 1]; }
      float mu = s1 * (1.f / 256.f);
      float var = s2 * (1.f / 256.f) - mu * mu;
      muL[tid] = mu;
      rsL[tid] = rsqrtf(var + LN_EPS);
    }
    __syncthreads();
#pragma unroll
    for (int i = 0; i < 8; i++) {
      int rl = tr * 8 + i;
      size_t row = (size_t)(m0 + rl);
      float mu = muL[rl], rs = rsL[rl];
#pragma unroll
      for (int j = 0; j < 8; j++) {
        int col = tc * 8 + j;
        acc[i][j] = (acc[i][j] - mu) * rs * gam[col] + bet[col];
      }
#pragma unroll
      for (int j = 0; j < 8; j += 4) {
        float4 v = make_float4(acc[i][j], acc[i][j + 1], acc[i][j + 2], acc[i][j + 3]);
        *(float4*)&Cout[row * CC + tc * 8 + j] = v;
      }
    }
  }
}

// ---------------------------------------------------------------------------
// Fused attention, wave-per-token. Uses the linearity reorder:
//   qk[h,e]   = sum_d q[h*32+d] * Wk[e, h*32+d]
//   s[h,p]    = (qk[h,:] . T[p,:]) * w[p] / sqrt(32)   -> softmax over p
//   tc[h,e]   = sum_p (attn*conf)[h,p] * T[p,e]
//   out[c]    = sum_e tc[c/32, e] * Wv[e, c]
// qbuf is read (q) then overwritten (attn_out) per token row.
// ---------------------------------------------------------------------------
__global__ __launch_bounds__(256) void attn_kernel(float* qbuf,
                                                   const float* __restrict__ target,
                                                   const float* __restrict__ wts,
                                                   const float* __restrict__ conf,
                                                   const float* __restrict__ Wk,
                                                   const float* __restrict__ Wv) {
  __shared__ float scL[4][HH][PP];
  __shared__ float awL[4][HH][PP];
  __shared__ float tcl[4][HH][260];
  const int tid = threadIdx.x;
  const int w = tid >> 6, l = tid & 63;
  const int t = blockIdx.x * 4 + w;
  const float* qrow = qbuf + (size_t)t * CC;
  const float* trow = target + (size_t)t * PP * CC;

  // Phase 1: qk[h][j] for channels e = 4*l + j
  float qk[HH][4];
#pragma unroll
  for (int h = 0; h < HH; h++)
#pragma unroll
    for (int j = 0; j < 4; j++) qk[h][j] = 0.f;
#pragma unroll
  for (int h = 0; h < HH; h++) {
#pragma unroll
    for (int dd = 0; dd < 8; dd++) {
      float4 qv = *(const float4*)&qrow[h * DD + dd * 4];   // wave-uniform
#pragma unroll
      for (int j = 0; j < 4; j++) {
        float4 wv = *(const float4*)&Wk[(size_t)(4 * l + j) * CC + h * DD + dd * 4];
        qk[h][j] += qv.x * wv.x + qv.y * wv.y + qv.z * wv.z + qv.w * wv.w;
      }
    }
  }

  // Phase 2: scores (full-wave butterfly reduction per (h,p))
  const float rsD = 0.17677669529663687f;  // 1/sqrt(32)
  for (int p = 0; p < PP; p++) {
    float4 tv = *(const float4*)&trow[p * CC + 4 * l];
    float part[HH];
#pragma unroll
    for (int h = 0; h < HH; h++)
      part[h] = qk[h][0] * tv.x + qk[h][1] * tv.y + qk[h][2] * tv.z + qk[h][3] * tv.w;
#pragma unroll
    for (int m = 1; m < 64; m <<= 1)
#pragma unroll
      for (int h = 0; h < HH; h++) part[h] += __shfl_xor(part[h], m, 64);
    if (l == 0) {
      float wscale = wts[(size_t)t * PP + p] * rsD;
#pragma unroll
      for (int h = 0; h < HH; h++) scL[w][h][p] = part[h] * wscale;
    }
  }
  __syncthreads();

  // Phase 3: softmax over p; lane handles (h0=l>>4, p=l&15) and (h0+4, p)
  {
    int p = l & 15;
    int h0 = l >> 4, h1 = h0 + 4;
    float cf = conf[(size_t)t * PP + p];
    float x0 = scL[w][h0][p], x1 = scL[w][h1][p];
    float m0 = x0, m1 = x1;
#pragma unroll
    for (int m = 1; m < 16; m <<= 1) {
      m0 = fmaxf(m0, __shfl_xor(m0, m, 64));
      m1 = fmaxf(m1, __shfl_xor(m1, m, 64));
    }
    float e0 = expf(x0 - m0), e1 = expf(x1 - m1);
    float s0 = e0, s1 = e1;
#pragma unroll
    for (int m = 1; m < 16; m <<= 1) {
      s0 += __shfl_xor(s0, m, 64);
      s1 += __shfl_xor(s1, m, 64);
    }
    awL[w][h0][p] = e0 / s0 * cf;
    awL[w][h1][p] = e1 / s1 * cf;
  }
  __syncthreads();

  // Phase 4: tc[h][j] = sum_p aw[h][p] * T[p, 4l+j]
  float tc_[HH][4];
#pragma unroll
  for (int h = 0; h < HH; h++)
#pragma unroll
    for (int j = 0; j < 4; j++) tc_[h][j] = 0.f;
  for (int p = 0; p < PP; p++) {
    float4 tv = *(const float4*)&trow[p * CC + 4 * l];
#pragma unroll
    for (int h = 0; h < HH; h++) {
      float aw = awL[w][h][p];
      tc_[h][0] += aw * tv.x; tc_[h][1] += aw * tv.y;
      tc_[h][2] += aw * tv.z; tc_[h][3] += aw * tv.w;
    }
  }
#pragma unroll
  for (int h = 0; h < HH; h++) {
    float4 v = make_float4(tc_[h][0], tc_[h][1], tc_[h][2], tc_[h][3]);
    *(float4*)&tcl[w][h][4 * l] = v;
  }
  __syncthreads();

  // Phase 5: out[c] for c = 4l+j; head index h = c/32 = l>>3 (constant over j)
  const int hh = l >> 3;
  float o[4] = {0.f, 0.f, 0.f, 0.f};
  for (int e = 0; e < CC; e++) {
    float tcv = tcl[w][hh][e];
    float4 wv = *(const float4*)&Wv[(size_t)e * CC + 4 * l];
    o[0] += tcv * wv.x; o[1] += tcv * wv.y; o[2] += tcv * wv.z; o[3] += tcv * wv.w;
  }
  *(float4*)&qbuf[(size_t)t * CC + 4 * l] = make_float4(o[0], o[1], o[2], o[3]);
}

// ---------------------------------------------------------------------------
// Fused FFN: h = [src||msg] @ Wf1 -> gelu(erf) -> @ Wf2 -> LN -> +src residual.
// 64 rows per block; hidden (2048) processed in chunks of 64 so it never
// touches global memory.
// ---------------------------------------------------------------------------
__global__ __launch_bounds__(256) void ffn_kernel(const float* __restrict__ src,
                                                  const float* __restrict__ msg,
                                                  const float* __restrict__ Wf1,
                                                  const float* __restrict__ Wf2,
                                                  const float* __restrict__ g2,
                                                  const float* __restrict__ b2,
                                                  float* __restrict__ out) {
  __shared__ float AsT[32][68];    // [k][row] chunk of concat input
  __shared__ float W1s[32][68];    // [k][64 hid cols]
  __shared__ float hsT[64][68];    // [hid k2][row], post-gelu
  __shared__ float W2s[32][260];   // [k2][256 n]
  __shared__ float muL[64], rsL[64];
  const int tid = threadIdx.x;
  const int m0 = blockIdx.x * 64;
  const int tr = tid >> 5, tc = tid & 31;
  float acc[8][8];
#pragma unroll
  for (int i = 0; i < 8; i++)
#pragma unroll
    for (int j = 0; j < 8; j++) acc[i][j] = 0.f;

  for (int hc = 0; hc < FHID; hc += 64) {
    float acc2[8][2];
#pragma unroll
    for (int i = 0; i < 8; i++) { acc2[i][0] = 0.f; acc2[i][1] = 0.f; }

    for (int ks = 0; ks < FIN; ks += 32) {
#pragma unroll
      for (int i = 0; i < 2; i++) {      // stage A chunk (concat src||msg), transposed
        int lin = tid + i * 256, row = lin >> 3, kq = lin & 7;
        int kabs = ks + kq * 4;
        const float* base = (kabs < 256) ? &src[(size_t)(m0 + row) * CC + kabs]
                                         : &msg[(size_t)(m0 + row) * CC + kabs - 256];
        float4 av = *(const float4*)base;
        AsT[kq * 4 + 0][row] = av.x; AsT[kq * 4 + 1][row] = av.y;
        AsT[kq * 4 + 2][row] = av.z; AsT[kq * 4 + 3][row] = av.w;
      }
#pragma unroll
      for (int i = 0; i < 2; i++) {      // stage Wf1 chunk [32][64]
        int lin = tid + i * 256, wk = lin >> 4, wc = (lin & 15) * 4;
        *(float4*)&W1s[wk][wc] = *(const float4*)&Wf1[(size_t)(ks + wk) * FHID + hc + wc];
      }
      __syncthreads();
#pragma unroll
      for (int kk = 0; kk < 32; kk++) {
        float a[8];
        *(float4*)&a[0] = *(const float4*)&AsT[kk][tr * 8];
        *(float4*)&a[4] = *(const float4*)&AsT[kk][tr * 8 + 4];
        float b0 = W1s[kk][tc * 2], b1 = W1s[kk][tc * 2 + 1];
#pragma unroll
        for (int i = 0; i < 8; i++) { acc2[i][0] += a[i] * b0; acc2[i][1] += a[i] * b1; }
      }
      __syncthreads();
    }

    // exact gelu, write transposed hidden tile
#pragma unroll
    for (int i = 0; i < 8; i++)
#pragma unroll
      for (int j = 0; j < 2; j++) {
        float x = acc2[i][j];
        hsT[tc * 2 + j][tr * 8 + i] = 0.5f * x * (1.0f + erff(x * 0.70710678118654752f));
      }
    __syncthreads();

    for (int k2s = 0; k2s < 64; k2s += 32) {
#pragma unroll
      for (int i = 0; i < 8; i++) {      // stage Wf2 chunk [32][256]
        int lin = tid + i * 256, wk = lin >> 6, wc = (lin & 63) * 4;
        *(float4*)&W2s[wk][wc] = *(const float4*)&Wf2[(size_t)(hc + k2s + wk) * CC + wc];
      }
      __syncthreads();
#pragma unroll
      for (int kk = 0; kk < 32; kk++) {
        float a[8], b[8];
        *(float4*)&a[0] = *(const float4*)&hsT[k2s + kk][tr * 8];
        *(float4*)&a[4] = *(const float4*)&hsT[k2s + kk][tr * 8 + 4];
        *(float4*)&b[0] = *(const float4*)&W2s[kk][tc * 8];
        *(float4*)&b[4] = *(const float4*)&W2s[kk][tc * 8 + 4];
#pragma unroll
        for (int i = 0; i < 8; i++)
#pragma unroll
          for (int j = 0; j < 8; j++) acc[i][j] += a[i] * b[j];
      }
      __syncthreads();
    }
  }

  // LayerNorm + residual epilogue; red[] aliases W2s.
  float (*red)[66] = (float (*)[66])&W2s[0][0];
#pragma unroll
  for (int i = 0; i < 8; i++) {
    float s1 = 0.f, s2 = 0.f;
#pragma unroll
    for (int j = 0; j < 8; j++) { s1 += acc[i][j]; s2 += acc[i][j] * acc[i][j]; }
    red[tr * 8 + i][tc * 2] = s1;
    red[tr * 8 + i][tc * 2 + 1] = s2;
  }
  __syncthreads();
  if (tid < 64) {
    float s1 = 0.f, s2 = 0.f;
    for (int c = 0; c < 32; c++) { s1 += red[tid][2 * c]; s2 += red[tid][2 * c + 1]; }
    float mu = s1 * (1.f / 256.f);
    float var = s2 * (1.f / 256.f) - mu * mu;
    muL[tid] = mu;
    rsL[tid] = rsqrtf(var + LN_EPS);
  }
  __syncthreads();
#pragma unroll
  for (int i = 0; i < 8; i++) {
    int rl = tr * 8 + i;
    size_t row = (size_t)(m0 + rl);
    float mu = muL[rl], rs = rsL[rl];
#pragma unroll
    for (int j = 0; j < 8; j += 4) {
      float4 sv = *(const float4*)&src[row * CC + tc * 8 + j];
      float4 v;
      v.x = sv.x + (acc[i][j + 0] - mu) * rs * g2[tc * 8 + j + 0] + b2[tc * 8 + j + 0];
      v.y = sv.y + (acc[i][j + 1] - mu) * rs * g2[tc * 8 + j + 1] + b2[tc * 8 + j + 1];
      v.z = sv.z + (acc[i][j + 2] - mu) * rs * g2[tc * 8 + j + 2] + b2[tc * 8 + j + 2];
      v.w = sv.w + (acc[i][j + 3] - mu) * rs * g2[tc * 8 + j + 3] + b2[tc * 8 + j + 3];
      *(float4*)&out[row * CC + tc * 8 + j] = v;
    }
  }
}

extern "C" void kernel_launch(void* const* d_in, const int* in_sizes, int n_in,
                              void* d_out, int out_size, void* d_ws, size_t ws_size,
                              hipStream_t stream) {
  const float* source = (const float*)d_in[0];
  const float* target = (const float*)d_in[1];
  const float* weights = (const float*)d_in[2];
  const float* conf   = (const float*)d_in[3];
  const float* Wq = (const float*)d_in[4];
  const float* Wk = (const float*)d_in[5];
  const float* Wv = (const float*)d_in[6];
  const float* Wm = (const float*)d_in[7];
  const float* g1 = (const float*)d_in[8];
  const float* b1 = (const float*)d_in[9];
  const float* Wf1 = (const float*)d_in[10];
  const float* Wf2 = (const float*)d_in[11];
  const float* g2 = (const float*)d_in[12];
  const float* b2 = (const float*)d_in[13];
  float* out = (float*)d_out;

  float* B1 = (float*)d_ws;                       // q, then attn_out (in-place)
  float* B2 = B1 + (size_t)T_TOK * CC;            // message (post-Wm LN)

  // 1) q = source @ Wq
  gemm256_kernel<0><<<T_TOK / 64, 256, 0, stream>>>(source, Wq, nullptr, nullptr, B1);
  // 2) fused attention -> attn_out (in B1)
  attn_kernel<<<T_TOK / 4, 256, 0, stream>>>(B1, target, weights, conf, Wk, Wv);
  // 3) message = LN(attn_out @ Wm) -> B2
  gemm256_kernel<1><<<T_TOK / 64, 256, 0, stream>>>(B1, Wm, g1, b1, B2);
  // 4) out = source + LN(gelu([src||msg] @ Wf1) @ Wf2)
  ffn_kernel<<<T_TOK / 64, 256, 0, stream>>>(source, B2, Wf1, Wf2, g2, b2, out);
}

// Round 2
// 588.637 us; speedup vs baseline: 4.0130x; 4.0130x over previous
//
#include <hip/hip_runtime.h>
#include <hip/hip_bf16.h>
#include <math.h>

#define T_TOK 16384
#define CC 256
#define PP 16
#define HH 8
#define DD 32
#define LN_EPS 1e-5f
#define CHUNK 2048

typedef __attribute__((ext_vector_type(8))) short bf16x8_t;
typedef __attribute__((ext_vector_type(4))) float f32x4_t;

__device__ __forceinline__ unsigned short f2bf(float x) {
  __hip_bfloat16 h = __float2bfloat16(x);
  return *reinterpret_cast<unsigned short*>(&h);
}
__device__ __forceinline__ float bf2f(unsigned short u) {
  union { unsigned int i; float f; } v; v.i = ((unsigned int)u) << 16; return v.f;
}

// ---------------------------------------------------------------------------
// Prep: f32 -> bf16 rowmajor copy
// ---------------------------------------------------------------------------
__global__ __launch_bounds__(256) void cvt_bf16_kernel(const float* __restrict__ src,
                                                       unsigned short* __restrict__ dst) {
  int i = (blockIdx.x * 256 + threadIdx.x) * 4;
  float4 v = *(const float4*)&src[i];
  ushort4 o = make_ushort4(f2bf(v.x), f2bf(v.y), f2bf(v.z), f2bf(v.w));
  *(ushort4*)&dst[i] = o;
}

// Prep: transpose + cvt: dst[n][k] = bf16(src[k][n]); grid (K/64, N/64)
__global__ __launch_bounds__(256) void transpose_cvt_kernel(const float* __restrict__ src,
                                                            unsigned short* __restrict__ dst,
                                                            int K, int N) {
  __shared__ float tile[64][65];
  int k0 = blockIdx.x * 64, n0 = blockIdx.y * 64;
  int tid = threadIdx.x;
#pragma unroll
  for (int i = 0; i < 16; i++) {
    int lin = i * 256 + tid, r = lin >> 6, c = lin & 63;
    tile[r][c] = src[(size_t)(k0 + r) * N + n0 + c];
  }
  __syncthreads();
#pragma unroll
  for (int i = 0; i < 16; i++) {
    int lin = i * 256 + tid, n = lin >> 6, k = lin & 63;
    dst[(size_t)(n0 + n) * K + k0 + k] = f2bf(tile[k][n]);
  }
}

// Prep: Mt[(h*256+e)][c] = bf16( sum_d Wq[c][h*32+d] * Wk[e][h*32+d] )
__global__ __launch_bounds__(256) void precM_kernel(const float* __restrict__ Wq,
                                                    const float* __restrict__ Wk,
                                                    unsigned short* __restrict__ Mt) {
  int n = blockIdx.x;           // 0..2047
  int h = n >> 8, e = n & 255;
  int c = threadIdx.x;
  const float* wkrow = Wk + (size_t)e * CC + h * DD;
  const float* wqrow = Wq + (size_t)c * CC + h * DD;
  float s = 0.f;
#pragma unroll
  for (int d = 0; d < DD; d++) s += wqrow[d] * wkrow[d];
  Mt[(size_t)n * CC + c] = f2bf(s);
}

// ---------------------------------------------------------------------------
// MFMA GEMM: Out[M,*] = A[M,K] @ Bt^T   (Bt stored [N][K] bf16)
// BM=64, BN=256, BK=32; 512 threads = 8 waves (2 wr x 4 wc), wave = 32x64.
// EPI 0: raw bf16 store (strideO, col offset n0). EPI 1: LN(g,b) -> bf16.
// ---------------------------------------------------------------------------
template<int EPI>
__global__ __launch_bounds__(512) void mfma_gemm_kernel(
    const unsigned short* __restrict__ A, const unsigned short* __restrict__ Bt,
    unsigned short* __restrict__ Out, const float* __restrict__ gam,
    const float* __restrict__ bet, int K, int strideO) {
  __shared__ __align__(16) unsigned short As[64 * 32];
  __shared__ __align__(16) unsigned short Bs[256 * 32];
  __shared__ float redS[64][5], redQ[64][5];
  const int tid = threadIdx.x;
  const int wv = tid >> 6, l = tid & 63;
  const int wr = wv >> 2, wc = wv & 3;
  const int lr = l & 15, lq = l >> 4;
  const int m0 = blockIdx.x * 64;
  const int n0 = blockIdx.y * 256;

  f32x4_t acc[2][4];
#pragma unroll
  for (int m = 0; m < 2; m++)
#pragma unroll
    for (int n = 0; n < 4; n++) acc[m][n] = (f32x4_t){0.f, 0.f, 0.f, 0.f};

  for (int k0 = 0; k0 < K; k0 += 32) {
    if (tid < 256) {                       // stage A: 64 rows x 32 k
      int r = tid >> 2, s = tid & 3;
      int q = s ^ ((r >> 1) & 3);
      *(uint4*)&As[r * 32 + s * 8] = *(const uint4*)&A[(size_t)(m0 + r) * K + k0 + q * 8];
    }
#pragma unroll
    for (int it = 0; it < 2; it++) {       // stage B: 256 rows x 32 k
      int lin = it * 512 + tid;
      int r = lin >> 2, s = lin & 3;
      int q = s ^ ((r >> 1) & 3);
      *(uint4*)&Bs[r * 32 + s * 8] = *(const uint4*)&Bt[(size_t)(n0 + r) * K + k0 + q * 8];
    }
    __syncthreads();
    bf16x8_t af[2], bfr[4];
#pragma unroll
    for (int m = 0; m < 2; m++) {
      int r = wr * 32 + m * 16 + lr;
      int s = lq ^ ((r >> 1) & 3);
      af[m] = *(const bf16x8_t*)&As[r * 32 + s * 8];
    }
#pragma unroll
    for (int n = 0; n < 4; n++) {
      int r = wc * 64 + n * 16 + lr;
      int s = lq ^ ((r >> 1) & 3);
      bfr[n] = *(const bf16x8_t*)&Bs[r * 32 + s * 8];
    }
#pragma unroll
    for (int m = 0; m < 2; m++)
#pragma unroll
      for (int n = 0; n < 4; n++)
        acc[m][n] = __builtin_amdgcn_mfma_f32_16x16x32_bf16(af[m], bfr[n], acc[m][n], 0, 0, 0);
    __syncthreads();
  }

  if constexpr (EPI == 0) {
#pragma unroll
    for (int m = 0; m < 2; m++)
#pragma unroll
      for (int n = 0; n < 4; n++)
#pragma unroll
        for (int j = 0; j < 4; j++) {
          int rl = wr * 32 + m * 16 + lq * 4 + j;
          int col = n0 + wc * 64 + n * 16 + lr;
          Out[(size_t)(m0 + rl) * strideO + col] = f2bf(acc[m][n][j]);
        }
  } else {
    float s1[2][4], s2[2][4];
#pragma unroll
    for (int m = 0; m < 2; m++)
#pragma unroll
      for (int j = 0; j < 4; j++) {
        float a = 0.f, b = 0.f;
#pragma unroll
        for (int n = 0; n < 4; n++) { float x = acc[m][n][j]; a += x; b += x * x; }
        s1[m][j] = a; s2[m][j] = b;
      }
#pragma unroll
    for (int mask = 1; mask < 16; mask <<= 1)
#pragma unroll
      for (int m = 0; m < 2; m++)
#pragma unroll
        for (int j = 0; j < 4; j++) {
          s1[m][j] += __shfl_xor(s1[m][j], mask, 64);
          s2[m][j] += __shfl_xor(s2[m][j], mask, 64);
        }
    if (lr == 0) {
#pragma unroll
      for (int m = 0; m < 2; m++)
#pragma unroll
        for (int j = 0; j < 4; j++) {
          int rl = wr * 32 + m * 16 + lq * 4 + j;
          redS[rl][wc] = s1[m][j];
          redQ[rl][wc] = s2[m][j];
        }
    }
    __syncthreads();
#pragma unroll
    for (int m = 0; m < 2; m++)
#pragma unroll
      for (int j = 0; j < 4; j++) {
        int rl = wr * 32 + m * 16 + lq * 4 + j;
        float ts = redS[rl][0] + redS[rl][1] + redS[rl][2] + redS[rl][3];
        float tq = redQ[rl][0] + redQ[rl][1] + redQ[rl][2] + redQ[rl][3];
        float mu = ts * (1.f / 256.f);
        float var = tq * (1.f / 256.f) - mu * mu;
        float rs = rsqrtf(var + LN_EPS);
#pragma unroll
        for (int n = 0; n < 4; n++) {
          int col = wc * 64 + n * 16 + lr;
          float v = (acc[m][n][j] - mu) * rs * gam[col] + bet[col];
          Out[(size_t)(m0 + rl) * strideO + col] = f2bf(v);
        }
      }
  }
}

// ---------------------------------------------------------------------------
// Attention: wave-per-token (4 tokens / 256-thr block).
// qk comes precomputed (QKc bf16 [CHUNK][2048]); target cached in registers.
// ---------------------------------------------------------------------------
__global__ __launch_bounds__(256) void attn_kernel(const unsigned short* __restrict__ QKc,
                                                   const float* __restrict__ target,
                                                   const float* __restrict__ wts,
                                                   const float* __restrict__ conf,
                                                   const unsigned short* __restrict__ WVb,
                                                   unsigned short* __restrict__ AO,
                                                   int t0) {
  __shared__ float scL[4][HH][PP];
  __shared__ float awL[4][HH][PP];
  __shared__ float tcl[4][HH][260];
  const int tid = threadIdx.x;
  const int w = tid >> 6, l = tid & 63;
  const int tl = blockIdx.x * 4 + w;
  const int t = t0 + tl;
  const float* trow = target + (size_t)t * PP * CC;

  // qk[h][j] for channels e = 4l+j
  float qk[HH][4];
  const unsigned short* qkrow = QKc + (size_t)tl * 2048;
#pragma unroll
  for (int h = 0; h < HH; h++) {
    ushort4 u = *(const ushort4*)&qkrow[h * 256 + 4 * l];
    qk[h][0] = bf2f(u.x); qk[h][1] = bf2f(u.y); qk[h][2] = bf2f(u.z); qk[h][3] = bf2f(u.w);
  }
  // cache target rows (read once)
  float4 tv[PP];
#pragma unroll
  for (int p = 0; p < PP; p++) tv[p] = *(const float4*)&trow[p * CC + 4 * l];

  // scores
  const float rsD = 0.17677669529663687f;
#pragma unroll
  for (int p = 0; p < PP; p++) {
    float part[HH];
#pragma unroll
    for (int h = 0; h < HH; h++)
      part[h] = qk[h][0] * tv[p].x + qk[h][1] * tv[p].y + qk[h][2] * tv[p].z + qk[h][3] * tv[p].w;
#pragma unroll
    for (int m = 1; m < 64; m <<= 1)
#pragma unroll
      for (int h = 0; h < HH; h++) part[h] += __shfl_xor(part[h], m, 64);
    if (l == 0) {
      float wscale = wts[(size_t)t * PP + p] * rsD;
#pragma unroll
      for (int h = 0; h < HH; h++) scL[w][h][p] = part[h] * wscale;
    }
  }
  __syncthreads();

  // softmax over p
  {
    int p = l & 15;
    int h0 = l >> 4, h1 = h0 + 4;
    float cf = conf[(size_t)t * PP + p];
    float x0 = scL[w][h0][p], x1 = scL[w][h1][p];
    float m0 = x0, m1 = x1;
#pragma unroll
    for (int m = 1; m < 16; m <<= 1) {
      m0 = fmaxf(m0, __shfl_xor(m0, m, 64));
      m1 = fmaxf(m1, __shfl_xor(m1, m, 64));
    }
    float e0 = expf(x0 - m0), e1 = expf(x1 - m1);
    float s0 = e0, s1 = e1;
#pragma unroll
    for (int m = 1; m < 16; m <<= 1) {
      s0 += __shfl_xor(s0, m, 64);
      s1 += __shfl_xor(s1, m, 64);
    }
    awL[w][h0][p] = e0 / s0 * cf;
    awL[w][h1][p] = e1 / s1 * cf;
  }
  __syncthreads();

  // combine over p
  float tc_[HH][4];
#pragma unroll
  for (int h = 0; h < HH; h++)
#pragma unroll
    for (int j = 0; j < 4; j++) tc_[h][j] = 0.f;
#pragma unroll
  for (int p = 0; p < PP; p++) {
#pragma unroll
    for (int h = 0; h < HH; h++) {
      float aw = awL[w][h][p];
      tc_[h][0] += aw * tv[p].x; tc_[h][1] += aw * tv[p].y;
      tc_[h][2] += aw * tv[p].z; tc_[h][3] += aw * tv[p].w;
    }
  }
#pragma unroll
  for (int h = 0; h < HH; h++)
    *(float4*)&tcl[w][h][4 * l] = make_float4(tc_[h][0], tc_[h][1], tc_[h][2], tc_[h][3]);
  __syncthreads();

  // project by Wv (bf16): out[c] for c = 4l+j, head h = l>>3
  const int hh = l >> 3;
  float o[4] = {0.f, 0.f, 0.f, 0.f};
  for (int e = 0; e < CC; e++) {
    float tcv = tcl[w][hh][e];
    ushort4 wv4 = *(const ushort4*)&WVb[(size_t)e * CC + 4 * l];
    o[0] += tcv * bf2f(wv4.x); o[1] += tcv * bf2f(wv4.y);
    o[2] += tcv * bf2f(wv4.z); o[3] += tcv * bf2f(wv4.w);
  }
  *(ushort4*)&AO[(size_t)t * CC + 4 * l] = make_ushort4(f2bf(o[0]), f2bf(o[1]), f2bf(o[2]), f2bf(o[3]));
}

// ---------------------------------------------------------------------------
// Fused FFN (MFMA): out = src + LN(gelu([SB||MSG] @ Wf1) @ Wf2)
// BM=64 rows/block; hidden in 128-col chunks staged through swizzled LDS.
// ---------------------------------------------------------------------------
__global__ __launch_bounds__(512) void ffn_mfma_kernel(
    const unsigned short* __restrict__ SB, const unsigned short* __restrict__ MSG,
    const unsigned short* __restrict__ W1t,  // [2048][512]
    const unsigned short* __restrict__ W2t,  // [256][2048]
    const float* __restrict__ g2, const float* __restrict__ b2,
    const float* __restrict__ src, float* __restrict__ out) {
  __shared__ __align__(16) unsigned short As[64 * 32];
  __shared__ __align__(16) unsigned short W1s[128 * 32];
  __shared__ __align__(16) unsigned short hid[64 * 128];
  __shared__ __align__(16) unsigned short W2s[256 * 32];
  __shared__ float redS[64][5], redQ[64][5];
  const int tid = threadIdx.x;
  const int wv = tid >> 6, l = tid & 63;
  const int wr = wv >> 2, wc = wv & 3;
  const int lr = l & 15, lq = l >> 4;
  const int m0 = blockIdx.x * 64;
  char* hidb = (char*)hid;

  f32x4_t acc[2][4];
#pragma unroll
  for (int m = 0; m < 2; m++)
#pragma unroll
    for (int n = 0; n < 4; n++) acc[m][n] = (f32x4_t){0.f, 0.f, 0.f, 0.f};

  for (int hc = 0; hc < 2048; hc += 128) {
    f32x4_t acc2[2][2];
#pragma unroll
    for (int m = 0; m < 2; m++)
#pragma unroll
      for (int n = 0; n < 2; n++) acc2[m][n] = (f32x4_t){0.f, 0.f, 0.f, 0.f};

    for (int ks = 0; ks < 16; ks++) {
      int k0 = ks * 32;
      if (tid < 256) {                     // stage A (concat)
        int r = tid >> 2, s = tid & 3;
        int q = s ^ ((r >> 1) & 3);
        const unsigned short* base = (k0 < 256)
            ? &SB[(size_t)(m0 + r) * CC + k0 + q * 8]
            : &MSG[(size_t)(m0 + r) * CC + (k0 - 256) + q * 8];
        *(uint4*)&As[r * 32 + s * 8] = *(const uint4*)base;
      }
      {                                    // stage W1 panel: 128 rows
        int r = tid >> 2, s = tid & 3;
        int q = s ^ ((r >> 1) & 3);
        *(uint4*)&W1s[r * 32 + s * 8] = *(const uint4*)&W1t[(size_t)(hc + r) * 512 + k0 + q * 8];
      }
      __syncthreads();
      bf16x8_t af[2], b1f[2];
#pragma unroll
      for (int m = 0; m < 2; m++) {
        int r = wr * 32 + m * 16 + lr;
        int s = lq ^ ((r >> 1) & 3);
        af[m] = *(const bf16x8_t*)&As[r * 32 + s * 8];
      }
#pragma unroll
      for (int n = 0; n < 2; n++) {
        int r = wc * 32 + n * 16 + lr;
        int s = lq ^ ((r >> 1) & 3);
        b1f[n] = *(const bf16x8_t*)&W1s[r * 32 + s * 8];
      }
#pragma unroll
      for (int m = 0; m < 2; m++)
#pragma unroll
        for (int n = 0; n < 2; n++)
          acc2[m][n] = __builtin_amdgcn_mfma_f32_16x16x32_bf16(af[m], b1f[n], acc2[m][n], 0, 0, 0);
      __syncthreads();
    }

    // gelu -> swizzled hid LDS
#pragma unroll
    for (int m = 0; m < 2; m++)
#pragma unroll
      for (int n = 0; n < 2; n++)
#pragma unroll
        for (int j = 0; j < 4; j++) {
          int row = wr * 32 + m * 16 + lq * 4 + j;
          int col = wc * 32 + n * 16 + lr;
          float x = acc2[m][n][j];
          float gl = 0.5f * x * (1.0f + erff(x * 0.70710678118654752f));
          int byte = (row * 256 + col * 2) ^ ((row & 7) << 4);
          *(unsigned short*)(hidb + byte) = f2bf(gl);
        }
    __syncthreads();

    // GEMM2: acc += hid[64x128] @ Wf2[hc..hc+128, :]
#pragma unroll
    for (int ks2 = 0; ks2 < 4; ks2++) {
      int kg = hc + ks2 * 32;
#pragma unroll
      for (int it = 0; it < 2; it++) {     // stage W2 panel: 256 rows
        int lin = it * 512 + tid;
        int r = lin >> 2, s = lin & 3;
        int q = s ^ ((r >> 1) & 3);
        *(uint4*)&W2s[r * 32 + s * 8] = *(const uint4*)&W2t[(size_t)r * 2048 + kg + q * 8];
      }
      __syncthreads();
      bf16x8_t ah[2], b2f[4];
#pragma unroll
      for (int m = 0; m < 2; m++) {
        int row = wr * 32 + m * 16 + lr;
        int byte = (row * 256 + ks2 * 64 + lq * 16) ^ ((row & 7) << 4);
        ah[m] = *(const bf16x8_t*)(hidb + byte);
      }
#pragma unroll
      for (int n = 0; n < 4; n++) {
        int r = wc * 64 + n * 16 + lr;
        int s = lq ^ ((r >> 1) & 3);
        b2f[n] = *(const bf16x8_t*)&W2s[r * 32 + s * 8];
      }
#pragma unroll
      for (int m = 0; m < 2; m++)
#pragma unroll
        for (int n = 0; n < 4; n++)
          acc[m][n] = __builtin_amdgcn_mfma_f32_16x16x32_bf16(ah[m], b2f[n], acc[m][n], 0, 0, 0);
      __syncthreads();
    }
  }

  // LN + residual epilogue
  float s1[2][4], s2[2][4];
#pragma unroll
  for (int m = 0; m < 2; m++)
#pragma unroll
    for (int j = 0; j < 4; j++) {
      float a = 0.f, b = 0.f;
#pragma unroll
      for (int n = 0; n < 4; n++) { float x = acc[m][n][j]; a += x; b += x * x; }
      s1[m][j] = a; s2[m][j] = b;
    }
#pragma unroll
  for (int mask = 1; mask < 16; mask <<= 1)
#pragma unroll
    for (int m = 0; m < 2; m++)
#pragma unroll
      for (int j = 0; j < 4; j++) {
        s1[m][j] += __shfl_xor(s1[m][j], mask, 64);
        s2[m][j] += __shfl_xor(s2[m][j], mask, 64);
      }
  if (lr == 0) {
#pragma unroll
    for (int m = 0; m < 2; m++)
#pragma unroll
      for (int j = 0; j < 4; j++) {
        int rl = wr * 32 + m * 16 + lq * 4 + j;
        redS[rl][wc] = s1[m][j];
        redQ[rl][wc] = s2[m][j];
      }
  }
  __syncthreads();
#pragma unroll
  for (int m = 0; m < 2; m++)
#pragma unroll
    for (int j = 0; j < 4; j++) {
      int rl = wr * 32 + m * 16 + lq * 4 + j;
      float ts = redS[rl][0] + redS[rl][1] + redS[rl][2] + redS[rl][3];
      float tq = redQ[rl][0] + redQ[rl][1] + redQ[rl][2] + redQ[rl][3];
      float mu = ts * (1.f / 256.f);
      float var = tq * (1.f / 256.f) - mu * mu;
      float rs = rsqrtf(var + LN_EPS);
      size_t rowg = (size_t)(m0 + rl);
#pragma unroll
      for (int n = 0; n < 4; n++) {
        int col = wc * 64 + n * 16 + lr;
        float v = src[rowg * CC + col] + (acc[m][n][j] - mu) * rs * g2[col] + b2[col];
        out[rowg * CC + col] = v;
      }
    }
}

extern "C" void kernel_launch(void* const* d_in, const int* in_sizes, int n_in,
                              void* d_out, int out_size, void* d_ws, size_t ws_size,
                              hipStream_t stream) {
  const float* source = (const float*)d_in[0];
  const float* target = (const float*)d_in[1];
  const float* weights = (const float*)d_in[2];
  const float* conf   = (const float*)d_in[3];
  const float* Wq = (const float*)d_in[4];
  const float* Wk = (const float*)d_in[5];
  const float* Wv = (const float*)d_in[6];
  const float* Wm = (const float*)d_in[7];
  const float* g1 = (const float*)d_in[8];
  const float* b1 = (const float*)d_in[9];
  const float* Wf1 = (const float*)d_in[10];
  const float* Wf2 = (const float*)d_in[11];
  const float* g2 = (const float*)d_in[12];
  const float* b2 = (const float*)d_in[13];
  float* out = (float*)d_out;

  unsigned short* SB   = (unsigned short*)d_ws;                 // [16384][256]
  unsigned short* MSGb = SB + (size_t)T_TOK * CC;               // [16384][256]
  unsigned short* QKc  = MSGb + (size_t)T_TOK * CC;             // [2048][2048]
  unsigned short* Mt   = QKc + (size_t)CHUNK * 2048;            // [2048][256]
  unsigned short* WMt  = Mt + (size_t)2048 * 256;               // [256][256]
  unsigned short* WF1t = WMt + (size_t)256 * 256;               // [2048][512]
  unsigned short* WF2t = WF1t + (size_t)2048 * 512;             // [256][2048]
  unsigned short* WVb  = WF2t + (size_t)256 * 2048;             // [256][256] rowmajor
  unsigned short* AObf = (unsigned short*)d_out;                // parked in d_out

  // prep
  cvt_bf16_kernel<<<T_TOK * CC / 1024, 256, 0, stream>>>(source, SB);
  cvt_bf16_kernel<<<CC * CC / 1024, 256, 0, stream>>>(Wv, WVb);
  transpose_cvt_kernel<<<dim3(4, 4), 256, 0, stream>>>(Wm, WMt, 256, 256);
  transpose_cvt_kernel<<<dim3(8, 32), 256, 0, stream>>>(Wf1, WF1t, 512, 2048);
  transpose_cvt_kernel<<<dim3(32, 4), 256, 0, stream>>>(Wf2, WF2t, 2048, 256);
  precM_kernel<<<2048, 256, 0, stream>>>(Wq, Wk, Mt);

  // attention pipeline, chunked
  for (int c = 0; c < T_TOK / CHUNK; c++) {
    int t0 = c * CHUNK;
    mfma_gemm_kernel<0><<<dim3(CHUNK / 64, 8), 512, 0, stream>>>(
        SB + (size_t)t0 * CC, Mt, QKc, nullptr, nullptr, 256, 2048);
    attn_kernel<<<CHUNK / 4, 256, 0, stream>>>(QKc, target, weights, conf, WVb, AObf, t0);
  }
  // message = LN(AO @ Wm)
  mfma_gemm_kernel<1><<<dim3(T_TOK / 64, 1), 512, 0, stream>>>(
      AObf, WMt, MSGb, g1, b1, 256, 256);
  // out = src + LN(gelu([SB||MSG] @ Wf1) @ Wf2)
  ffn_mfma_kernel<<<T_TOK / 64, 512, 0, stream>>>(SB, MSGb, WF1t, WF2t, g2, b2, source, out);
}